// Round 1
// baseline (1303.801 us; speedup 1.0000x reference)
//
#include <hip/hip_runtime.h>
#include <stdint.h>

typedef int   v4i  __attribute__((ext_vector_type(4)));
typedef int   v16i __attribute__((ext_vector_type(16)));
typedef float v4f  __attribute__((ext_vector_type(4)));

constexpr int M = 256, N = 28672, K = 8192;
constexpr int BN = 64, BK = 64;
constexpr int KITERS = K / BK;  // 128
// q is stored pre-tiled: 128 kblocks x 16384 bytes; kblock image is exactly the
// MFMA A-fragment order: addr(g, ks, lane) = g*2048 + ks*1024 + lane*16.
// => A fragments are direct, fully-coalesced global dwordx4 loads (L2-resident).

// ---------------------------------------------------------------------------
// Kernel 1: per-token int8 quant (x arrives as float32 per harness dtype rules)
// ---------------------------------------------------------------------------
__global__ __launch_bounds__(256) void quant_kernel(
    const float* __restrict__ x, int8_t* __restrict__ q,
    float* __restrict__ scales)
{
  const int m = blockIdx.x, t = threadIdx.x;
  const float* xr = x + (size_t)m * K;

  v4f v[8];
  float amax = 0.0f;
#pragma unroll
  for (int i = 0; i < 8; ++i) {
    v[i] = *(const v4f*)(xr + (i * 256 + t) * 4);  // coalesced float4
#pragma unroll
    for (int e = 0; e < 4; ++e) amax = fmaxf(amax, fabsf(v[i][e]));
  }
#pragma unroll
  for (int off = 32; off >= 1; off >>= 1)
    amax = fmaxf(amax, __shfl_xor(amax, off, 64));
  __shared__ float wmax[4];
  if ((t & 63) == 0) wmax[t >> 6] = amax;
  __syncthreads();
  amax = fmaxf(fmaxf(wmax[0], wmax[1]), fmaxf(wmax[2], wmax[3]));

  const float s = fmaxf(amax, 1e-5f) / 127.0f;  // IEEE div, matches ref
  if (t == 0) scales[m] = s;

  // element k = (i*256+t)*4 + e -> kblock = i*16 + (t>>4), s4 = (t>>2)&3
  const int s4 = (t >> 2) & 3;
  const size_t slotoff =
      (size_t)((m >> 5) * 128 + s4 * 32 + (m & 31)) * 16 + (t & 3) * 4;
#pragma unroll
  for (int i = 0; i < 8; ++i) {
    const int b0 = __float2int_rn(v[i][0] / s) & 255;
    const int b1 = __float2int_rn(v[i][1] / s) & 255;
    const int b2 = __float2int_rn(v[i][2] / s) & 255;
    const int b3 = __float2int_rn(v[i][3] / s);
    const int pk = b0 | (b1 << 8) | (b2 << 16) | (b3 << 24);
    const int kblock = i * 16 + (t >> 4);
    *(int*)(q + (size_t)kblock * 16384 + slotoff) = pk;
  }
}

// ---------------------------------------------------------------------------
// Kernel 2: int8 GEMM, deep-pipelined B stream.
//
// vs previous version: __syncthreads() (which compiles to a FULL
// vmcnt(0)+lgkmcnt(0) drain -> ~26% of HBM BW) is replaced by
// raw s_barrier + lgkmcnt(0) (publishes ds_writes only). All register-data
// waits are left to the compiler's exact counted vmcnt insertion, so the
// HBM weight stream stays in flight across barriers.
//
// B pipeline is depth-2: B(it+2) issued at iter it (reg set toggles by
// parity), written to LDS at iter it+1, consumed at iter it+2 -> ~2 full
// iterations of latency cover. A(it) is loaded at the TOP of iter it,
// *before* loadB(it+2): in-order vmcnt retirement means the MFMA's
// vmcnt(4) wait (for A) never drains the deep B prefetch. A comes from the
// 2 MB L2-resident q, so its ~200cy exposure hides under other waves.
// ---------------------------------------------------------------------------
__global__ __launch_bounds__(256, 3) void gemm_kernel(
    const int8_t* __restrict__ q, const int* __restrict__ wgt,
    const float* __restrict__ ascale, const float* __restrict__ cscale,
    const float* __restrict__ bias, float* __restrict__ out)
{
  __shared__ __align__(16) int8_t Bbuf[2][4096];
  __shared__ float ldsS[256];

  const int tid  = threadIdx.x;
  const int lane = tid & 63;
  const int wv   = tid >> 6;
  const int n0   = blockIdx.x * BN;

  ldsS[tid] = ascale[tid];  // M == 256 == blockDim.x

  // B load mapping (coalesced): instr j covers rows wv*16 + j*4 + (lane>>4),
  // each row: 16 lanes x 16 ints = 1 KB contiguous.
  const int brow0 = wv * 16 + (lane >> 4);
  const int* bsrc = wgt + (size_t)(n0 + brow0) * K + (lane & 15) * 4;

  v4i bvE[4], bvO[4];  // B(k) lives in (k&1 ? bvO : bvE)

  auto loadB = [&](int it, v4i* bv) {
#pragma unroll
    for (int j = 0; j < 4; ++j)
      bv[j] = *(const v4i*)(bsrc + (size_t)j * 4 * K + it * 64);
  };
  auto writeB = [&](int8_t* Bb, const v4i* bv) {
#pragma unroll
    for (int j = 0; j < 4; ++j) {
      const int pk = (bv[j][0] & 255) | ((bv[j][1] & 255) << 8) |
                     ((bv[j][2] & 255) << 16) | (bv[j][3] << 24);
      const int R = brow0 + j * 4;
      *(int*)(Bb + (R >> 5) * 2048 + ((lane & 15) >> 2) * 512 + (R & 31) * 16 +
              (lane & 3) * 4) = pk;
    }
  };

  // A fragments straight from pre-tiled q (1 KB contiguous per wave-instr).
  const int8_t* abase = q + (size_t)(2 * wv) * 2048 + lane * 16;
  v4i a[2][2];
  auto loadA = [&](int it) {
#pragma unroll
    for (int mi = 0; mi < 2; ++mi)
#pragma unroll
      for (int ks = 0; ks < 2; ++ks)
        a[mi][ks] =
            *(const v4i*)(abase + (size_t)it * 16384 + mi * 2048 + ks * 1024);
  };

  v16i acc[2][2];
#pragma unroll
  for (int i = 0; i < 2; ++i)
#pragma unroll
    for (int j = 0; j < 2; ++j)
#pragma unroll
      for (int e = 0; e < 16; ++e) acc[i][j][e] = 0;

  // publish-only barrier: waits LDS ops, leaves global loads in flight
#define PUB_BARRIER()                                        \
  do {                                                       \
    asm volatile("s_waitcnt lgkmcnt(0)" ::: "memory");       \
    __builtin_amdgcn_s_barrier();                            \
  } while (0)

  // prologue: B(0)->bvE->LDS0 (waits only bvE, vmcnt(4)); B(1)->bvO in flight
  loadB(0, bvE);
  loadB(1, bvO);
  writeB(&Bbuf[0][0], bvE);
  PUB_BARRIER();  // also publishes ldsS

  // Iter it (parity P): read Bbuf[P] (holds B(it)); issue B(it+2) into the
  // set freed when B(it) went to LDS last iter; write B(it+1) -> Bbuf[P^1].
#define GEMM_STEP(IT, BV_CUR, BV_NXT, PBUF)                                    \
  {                                                                            \
    loadA(IT); /* issued BEFORE loadB(it+2): vmcnt(4) at MFMA keeps B deep */  \
    if ((IT) + 2 < KITERS) loadB((IT) + 2, BV_CUR);                            \
    const int8_t* Bb = &Bbuf[PBUF][0];                                         \
    const int lb = lane * 16;                                                  \
    _Pragma("unroll")                                                          \
    for (int ks = 0; ks < 2; ++ks) {                                           \
      const v4i b0 = *(const v4i*)(Bb + 0 * 2048 + ks * 1024 + lb);            \
      const v4i b1 = *(const v4i*)(Bb + 1 * 2048 + ks * 1024 + lb);            \
      acc[0][0] = __builtin_amdgcn_mfma_i32_32x32x32_i8(a[0][ks], b0,          \
                                                        acc[0][0], 0, 0, 0);   \
      acc[0][1] = __builtin_amdgcn_mfma_i32_32x32x32_i8(a[0][ks], b1,          \
                                                        acc[0][1], 0, 0, 0);   \
      acc[1][0] = __builtin_amdgcn_mfma_i32_32x32x32_i8(a[1][ks], b0,          \
                                                        acc[1][0], 0, 0, 0);   \
      acc[1][1] = __builtin_amdgcn_mfma_i32_32x32x32_i8(a[1][ks], b1,          \
                                                        acc[1][1], 0, 0, 0);   \
    }                                                                          \
    if ((IT) + 1 < KITERS) {                                                   \
      writeB(&Bbuf[(PBUF) ^ 1][0], BV_NXT); /* B(it+1) provably done */        \
      PUB_BARRIER();                                                           \
    }                                                                          \
  }

  for (int it = 0; it < KITERS; it += 2) {
    GEMM_STEP(it, bvE, bvO, 0);
    GEMM_STEP(it + 1, bvO, bvE, 1);
  }
#undef GEMM_STEP
#undef PUB_BARRIER

  // epilogue: out[m,n] = acc * ascale[m] * cscale[n] + bias[n]
  // 32x32 C/D mapping (m74/m101): col = lane&31, row = (reg&3)+8*(reg>>2)+4*(lane>>5)
#pragma unroll
  for (int mi = 0; mi < 2; ++mi)
#pragma unroll
    for (int ni = 0; ni < 2; ++ni) {
      const int n_g = n0 + ni * 32 + (lane & 31);
      const float csn = cscale[n_g];
      const float bn  = bias[n_g];
      const int mbase = 64 * wv + mi * 32 + 4 * (lane >> 5);
#pragma unroll
      for (int reg = 0; reg < 16; ++reg) {
        const int mrow = mbase + (reg & 3) + 8 * (reg >> 2);
        out[(size_t)mrow * N + n_g] =
            (float)acc[mi][ni][reg] * ldsS[mrow] * csn + bn;
      }
    }
}

// ---------------------------------------------------------------------------
extern "C" void kernel_launch(void* const* d_in, const int* in_sizes, int n_in,
                              void* d_out, int out_size, void* d_ws, size_t ws_size,
                              hipStream_t stream) {
  const float* x      = (const float*)d_in[0];   // f16 in ref -> f32 on device
  const int*   wgt    = (const int*)d_in[1];     // int8 in ref -> int32 on device
  const float* cscale = (const float*)d_in[2];
  const float* bias   = (const float*)d_in[3];   // f16 in ref -> f32 on device
  float* out = (float*)d_out;

  int8_t* q      = (int8_t*)d_ws;                            // 2 MB, pre-tiled
  float*  ascale = (float*)((int8_t*)d_ws + (size_t)M * K);  // 256 f32

  quant_kernel<<<M, 256, 0, stream>>>(x, q, ascale);
  gemm_kernel<<<N / BN, 256, 0, stream>>>(q, wgt, ascale, cscale, bias, out);
}